// Round 5
// baseline (1508.012 us; speedup 1.0000x reference)
//
#include <hip/hip_runtime.h>
#include <hip/hip_bf16.h>
#include <hip/hip_cooperative_groups.h>

namespace cg = cooperative_groups;
typedef __hip_bfloat16 bf16;

#define NEG_SLOPE 0.01f
#define FGW 0.1f

__device__ __forceinline__ float b2f(bf16 v) { return __bfloat162float(v); }

// flagged boundary load: isbf=1 -> data is bf16, else f32
__device__ __forceinline__ float ldf(const void* p, size_t i, int isbf) {
    return isbf ? b2f(((const bf16*)p)[i]) : ((const float*)p)[i];
}

__device__ __forceinline__ float waveReduceSum(float v) {
#pragma unroll
    for (int o = 32; o > 0; o >>= 1) v += __shfl_down(v, o, 64);
    return v;
}

#define ATOMIC_ADD_F32(p, v) unsafeAtomicAdd((p), (v))

// 256-thread inclusive block scan in LDS (ilds = 256 ints); ilds[255] = total after return
__device__ __forceinline__ int blockScanIncl(int v, int* ilds) {
    const int t = threadIdx.x;
    ilds[t] = v;
    __syncthreads();
    for (int o = 1; o < 256; o <<= 1) {
        int add = (t >= o) ? ilds[t - o] : 0;
        __syncthreads();
        ilds[t] += add;
        __syncthreads();
    }
    return ilds[t];
}

__global__ __launch_bounds__(256, 4) void k_fused(
    const void* __restrict__ x, const int* __restrict__ ei,
    const void* __restrict__ W1, const void* __restrict__ attl1, const void* __restrict__ attr1,
    const void* __restrict__ W2, const void* __restrict__ attl2, const void* __restrict__ attr2,
    const void* __restrict__ fcw, const void* __restrict__ fcb, void* __restrict__ y,
    float* __restrict__ ws, int N, int E, int G) {

    cg::grid_group grid = cg::this_grid();
    const int t = threadIdx.x;
    const int bid = blockIdx.x;
    const int gtid = bid * 256 + t;
    const int gsz = G * 256;

    // ---- workspace layout (must cover ~525N + E + 2052 floats ≈ 108 MB) ----
    float* h1    = ws;
    float* x2    = h1 + (size_t)N * 256;
    float* al1   = x2 + (size_t)N * 256;
    float* ar1   = al1 + (size_t)N * 4;
    float* logr  = ar1 + (size_t)N * 4;
    float* al2v  = logr + N;
    float* ar2v  = al2v + N;
    float* logr2 = ar2v + N;
    int* rowptr  = (int*)(logr2 + N);
    int* deg     = rowptr + (N + 1);
    int* cursor  = deg + N;
    int* csr_src = cursor + N;
    int* bsum    = csr_src + E;          // 2048 ints
    float* sscal = (float*)(bsum + 2048);
    float* h2    = h1;                   // layer2 overlays h1 region

    __shared__ float smem[16 * 256 + 64];
    int* ilds = (int*)smem;
    float* sextra = smem + 16 * 256;

    // ---- dtype detect (per block, wave 0; no global flag needed) ----
    if (t < 64) {
        const unsigned short* xr = (const unsigned short*)x;
        int big = 0;
        for (int i = t; i < 256; i += 64) {
            int ex = (xr[i] >> 7) & 0xFF;
            if (ex >= 0xBF) big = 1;  // |bf16| >= 2^64 impossible for N(0,1) data
        }
        unsigned long long mk = __ballot(big);
        if (t == 0) ilds[0] = (mk == 0ull) ? 1 : 0;
    }
    __syncthreads();
    const int isbf = ilds[0];
    __syncthreads();

    // ---- ph0: zero accumulators (ws is re-poisoned each call) ----
    for (int i = gtid; i < N; i += gsz) { deg[i] = 0; cursor[i] = 0; }
    if (gtid == 0) { sscal[0] = 0.f; sscal[1] = 0.f; }
    grid.sync();

    // ---- ph1: degree histogram over dst ----
    for (int e = gtid; e < E; e += gsz) atomicAdd(&deg[ei[E + e]], 1);
    grid.sync();

    // ---- ph2: two-level exclusive scan -> rowptr ----
    const int C = (N + G - 1) / G;  // chunk per block
    {
        int start = bid * C;
        int cend = min(N, start + C);
        int s = 0;
        for (int i = start + t; i < cend; i += 256) s += deg[i];
        blockScanIncl(s, ilds);
        if (t == 0) bsum[bid] = ilds[255];
    }
    grid.sync();
    if (bid == 0) {  // scan the G block sums
        const int K = (G + 255) / 256;  // <= 8
        int v[8], lsum = 0;
        for (int k = 0; k < K; k++) { int i = t * K + k; v[k] = (i < G) ? bsum[i] : 0; lsum += v[k]; }
        int incl = blockScanIncl(lsum, ilds);
        int total = ilds[255];
        int excl = incl - lsum;
        for (int k = 0; k < K; k++) { int i = t * K + k; if (i < G) bsum[i] = excl; excl += v[k]; }
        if (t == 0) rowptr[N] = total;
    }
    grid.sync();
    {
        int start = bid * C;
        int cend = min(N, start + C);
        int carry = bsum[bid];
        for (int base = start; base < cend; base += 256) {
            int i = base + t;
            int dv = (i < cend) ? deg[i] : 0;
            int incl = blockScanIncl(dv, ilds);
            if (i < cend) rowptr[i] = carry + incl - dv;
            carry += ilds[255];
            __syncthreads();
        }
    }
    grid.sync();

    // ---- ph3: scatter edges into CSR ----
    for (int e = gtid; e < E; e += gsz) {
        int d = ei[E + e];
        int pos = atomicAdd(&cursor[d], 1);
        csr_src[rowptr[d] + pos] = ei[e];
    }
    grid.sync();

    // ---- ph4: GEMM1 (h1 = x@W1) + att stats + reward weights ----
    {
        const int T1 = (N + 15) / 16;
        float (*xs)[128] = (float(*)[128])smem;
        const int w = t >> 6, lane = t & 63;
        for (int tile = bid; tile < T1; tile += G) {
            const int row0 = tile * 16;
#pragma unroll
            for (int i = 0; i < 8; i++) {
                int idx = t + i * 256;
                int r = idx >> 7, c = idx & 127;
                int row = row0 + r;
                xs[r][c] = (row < N) ? ldf(x, (size_t)row * 128 + c, isbf) : 0.f;
            }
            __syncthreads();
            const int j = t;  // output column 0..255; wave w == head
            float acc[16];
#pragma unroll
            for (int r = 0; r < 16; r++) acc[r] = 0.f;
            for (int k = 0; k < 128; k += 4) {
                float w0 = ldf(W1, (size_t)(k + 0) * 256 + j, isbf);
                float w1 = ldf(W1, (size_t)(k + 1) * 256 + j, isbf);
                float w2 = ldf(W1, (size_t)(k + 2) * 256 + j, isbf);
                float w3 = ldf(W1, (size_t)(k + 3) * 256 + j, isbf);
#pragma unroll
                for (int r = 0; r < 16; r++) {
                    float4 xv = *reinterpret_cast<const float4*>(&xs[r][k]);
                    acc[r] += xv.x * w0 + xv.y * w1 + xv.z * w2 + xv.w * w3;
                }
            }
            float avl = ldf(attl1, j, isbf);
            float avr = ldf(attr1, j, isbf);
#pragma unroll
            for (int r = 0; r < 16; r++) {
                int row = row0 + r;
                float sl = waveReduceSum(acc[r] * avl);
                float sr = waveReduceSum(acc[r] * avr);
                if (row < N) {
                    h1[(size_t)row * 256 + j] = acc[r];
                    if (lane == 0) { al1[row * 4 + w] = sl; ar1[row * 4 + w] = sr; }
                }
            }
            if (t < 16) {
                int row = row0 + t;
                float rr = 0.f;
                if (row < N) {
                    float a = fabsf(xs[t][127]);
                    rr = 1.f / (a + 1e-6f);
                    logr[row] = logf(rr);
                }
                sextra[t] = rr;
            }
            __syncthreads();
            if (t == 0) {
                float s = 0.f;
#pragma unroll
                for (int i = 0; i < 16; i++) s += sextra[i];
                ATOMIC_ADD_F32(&sscal[0], s);
            }
            __syncthreads();
        }
    }
    grid.sync();

    // ---- ph5: agg1 (online softmax, 2-deep pipelined gather) -> x2 = elu(out1) ----
    {
        const int w = t >> 6, lane = t & 63, h = lane >> 4;
        const float gl = FGW * logf(fmaxf(sscal[0], 1e-12f));
        for (int d = bid * 4 + w; d < N; d += G * 4) {
            float al_h = al1[d * 4 + h];
            int beg = rowptr[d], end = rowptr[d + 1];
            float m = -INFINITY, sum = 0.f;
            float4 acc = {0.f, 0.f, 0.f, 0.f};
            if (beg < end) {
                int s = csr_src[beg];
                float arv = ar1[s * 4 + h];
                float lg = logr[s];
                float4 hv = *reinterpret_cast<const float4*>(&h1[(size_t)s * 256 + lane * 4]);
                for (int i = beg; i < end; i++) {
                    float c_ar = arv, c_lg = lg;
                    float4 c_hv = hv;
                    if (i + 1 < end) {  // wave-uniform prefetch
                        int s2 = csr_src[i + 1];
                        arv = ar1[s2 * 4 + h];
                        lg = logr[s2];
                        hv = *reinterpret_cast<const float4*>(&h1[(size_t)s2 * 256 + lane * 4]);
                    }
                    float a = al_h + c_ar;
                    a = fmaxf(a, NEG_SLOPE * a);          // leaky_relu
                    a = fmaf(FGW, c_lg, a - gl);          // + FGW*(log r - log S)
                    float mn = fmaxf(m, a);
                    float f = expf(m - mn);               // 0 on first edge
                    float e = expf(a - mn);
                    sum = sum * f + e;
                    acc.x = acc.x * f + e * c_hv.x;
                    acc.y = acc.y * f + e * c_hv.y;
                    acc.z = acc.z * f + e * c_hv.z;
                    acc.w = acc.w * f + e * c_hv.w;
                    m = mn;
                }
            }
            float inv = 1.f / (sum + 1e-16f);
            float4 o;
            o.x = acc.x * inv; o.y = acc.y * inv; o.z = acc.z * inv; o.w = acc.w * inv;
            o.x = (o.x > 0.f) ? o.x : expm1f(o.x);
            o.y = (o.y > 0.f) ? o.y : expm1f(o.y);
            o.z = (o.z > 0.f) ? o.z : expm1f(o.z);
            o.w = (o.w > 0.f) ? o.w : expm1f(o.w);
            *reinterpret_cast<float4*>(&x2[(size_t)d * 256 + lane * 4]) = o;
        }
    }
    grid.sync();

    // ---- ph6: GEMM2 (h2 = x2@W2) + att stats + reward weights ----
    {
        const int T2 = (N + 15) / 16;
        float (*xs)[256] = (float(*)[256])smem;
        const int j = t & 63, rg = t >> 6;
        for (int tile = bid; tile < T2; tile += G) {
            const int row0 = tile * 16;
#pragma unroll
            for (int i = 0; i < 16; i++) {
                int idx = t + i * 256;
                int r = idx >> 8, c = idx & 255;
                int row = row0 + r;
                xs[r][c] = (row < N) ? x2[(size_t)row * 256 + c] : 0.f;
            }
            __syncthreads();
            float acc[4] = {0.f, 0.f, 0.f, 0.f};
            for (int k = 0; k < 256; k += 4) {
                float w0 = ldf(W2, (size_t)(k + 0) * 64 + j, isbf);
                float w1 = ldf(W2, (size_t)(k + 1) * 64 + j, isbf);
                float w2 = ldf(W2, (size_t)(k + 2) * 64 + j, isbf);
                float w3 = ldf(W2, (size_t)(k + 3) * 64 + j, isbf);
#pragma unroll
                for (int i = 0; i < 4; i++) {
                    float4 xv = *reinterpret_cast<const float4*>(&xs[rg * 4 + i][k]);
                    acc[i] += xv.x * w0 + xv.y * w1 + xv.z * w2 + xv.w * w3;
                }
            }
            float avl = ldf(attl2, j, isbf);
            float avr = ldf(attr2, j, isbf);
#pragma unroll
            for (int i = 0; i < 4; i++) {
                int row = row0 + rg * 4 + i;
                float sl = waveReduceSum(acc[i] * avl);
                float sr = waveReduceSum(acc[i] * avr);
                if (row < N) {
                    h2[(size_t)row * 64 + j] = acc[i];
                    if (j == 0) { al2v[row] = sl; ar2v[row] = sr; }
                }
            }
            if (t < 16) {
                int row = row0 + t;
                float rr = 0.f;
                if (row < N) {
                    float a = fabsf(xs[t][255]);
                    rr = 1.f / (a + 1e-6f);
                    logr2[row] = logf(rr);
                }
                sextra[t] = rr;
            }
            __syncthreads();
            if (t == 0) {
                float s = 0.f;
#pragma unroll
                for (int i = 0; i < 16; i++) s += sextra[i];
                ATOMIC_ADD_F32(&sscal[1], s);
            }
            __syncthreads();
        }
    }
    grid.sync();

    // ---- ph7: agg2 (online softmax, pipelined) + ELU + FC -> y ----
    {
        const int w = t >> 6, lane = t & 63;
        const float gl2 = FGW * logf(fmaxf(sscal[1], 1e-12f));
        const float fcwv = ldf(fcw, lane, isbf);
        const float fcbv = ldf(fcb, 0, isbf);
        for (int d = bid * 4 + w; d < N; d += G * 4) {
            float al_d = al2v[d];
            int beg = rowptr[d], end = rowptr[d + 1];
            float m = -INFINITY, sum = 0.f, acc = 0.f;
            if (beg < end) {
                int s = csr_src[beg];
                float arv = ar2v[s];
                float lg = logr2[s];
                float hvs = h2[(size_t)s * 64 + lane];
                for (int i = beg; i < end; i++) {
                    float c_ar = arv, c_lg = lg, c_h = hvs;
                    if (i + 1 < end) {
                        int s2 = csr_src[i + 1];
                        arv = ar2v[s2];
                        lg = logr2[s2];
                        hvs = h2[(size_t)s2 * 64 + lane];
                    }
                    float a = al_d + c_ar;
                    a = fmaxf(a, NEG_SLOPE * a);
                    a = fmaf(FGW, c_lg, a - gl2);
                    float mn = fmaxf(m, a);
                    float f = expf(m - mn);
                    float e = expf(a - mn);
                    sum = sum * f + e;
                    acc = acc * f + e * c_h;
                    m = mn;
                }
            }
            float v = acc / (sum + 1e-16f);
            v = (v > 0.f) ? v : expm1f(v);
            float r = waveReduceSum(v * fcwv);
            if (lane == 0) {
                float o = r + fcbv;
                if (isbf) ((bf16*)y)[d] = __float2bfloat16(o);
                else      ((float*)y)[d] = o;
            }
        }
    }
}

extern "C" void kernel_launch(void* const* d_in, const int* in_sizes, int n_in,
                              void* d_out, int out_size, void* d_ws, size_t ws_size,
                              hipStream_t stream) {
    const void* x     = d_in[0];
    const int*  ei    = (const int*)d_in[1];
    const void* W1    = d_in[2];
    const void* attl1 = d_in[3];
    const void* attr1 = d_in[4];
    const void* W2    = d_in[5];
    const void* attl2 = d_in[6];
    const void* attr2 = d_in[7];
    const void* fcw   = d_in[8];
    const void* fcb   = d_in[9];
    void* y = d_out;

    int N = in_sizes[0] / 128;  // 50000
    int E = in_sizes[1] / 2;    // 800000
    float* ws = (float*)d_ws;

    // co-resident grid: maxB blocks/CU x 256 CUs (MI355X); bsum array allows G <= 2048
    int maxB = 0;
    if (hipOccupancyMaxActiveBlocksPerMultiprocessor(&maxB, (const void*)k_fused, 256, 0) != hipSuccess || maxB < 1)
        maxB = 2;
    if (maxB > 8) maxB = 8;
    int G = maxB * 256;

    void* ka[] = {&x, &ei, &W1, &attl1, &attr1, &W2, &attl2, &attr2,
                  &fcw, &fcb, &y, &ws, &N, &E, &G};
    hipLaunchCooperativeKernel((const void*)k_fused, dim3(G), dim3(256), ka, 0, stream);
}

// Round 7
// 613.357 us; speedup vs baseline: 2.4586x; 2.4586x over previous
//
#include <hip/hip_runtime.h>
#include <hip/hip_bf16.h>

typedef __hip_bfloat16 bf16;

#define NEG_SLOPE 0.01f
#define FGW 0.1f

__device__ __forceinline__ float b2f(bf16 v) { return __bfloat162float(v); }

// flagged boundary load: isbf=1 -> data is bf16, else f32
__device__ __forceinline__ float ldf(const void* p, size_t i, int isbf) {
    return isbf ? b2f(((const bf16*)p)[i]) : ((const float*)p)[i];
}

// bf16 bits (ushort) <-> float
__device__ __forceinline__ float bu2f(unsigned short u) {
    return __uint_as_float(((unsigned)u) << 16);
}
__device__ __forceinline__ unsigned short f2bu(float f) {
    return __bfloat16_as_ushort(__float2bfloat16(f));  // RNE
}

__device__ __forceinline__ float waveReduceSum(float v) {
#pragma unroll
    for (int o = 32; o > 0; o >>= 1) v += __shfl_down(v, o, 64);
    return v;
}

#define ATOMIC_ADD_F32(p, v) unsafeAtomicAdd((p), (v))

// ---------------- dtype detector: 1 block, 64 threads ----------------
__global__ void k_detect(const unsigned short* __restrict__ xr, int* __restrict__ flag) {
    int t = threadIdx.x;
    int big = 0;
    for (int i = t; i < 256; i += 64) {
        int ex = (xr[i] >> 7) & 0xFF;
        if (ex >= 0xBF) big = 1;   // |bf16| >= 2^64 impossible for N(0,1) data
    }
    unsigned long long m = __ballot(big);
    if (t == 0) *flag = (m == 0ull) ? 1 : 0;  // 1 => tensors are bf16
}

// ---------------- CSR build ----------------
__global__ __launch_bounds__(256) void k_deg(const int* __restrict__ ei, int* __restrict__ deg, int E) {
    int e = blockIdx.x * 256 + threadIdx.x;
    if (e >= E) return;
    atomicAdd(&deg[ei[E + e]], 1);
}

// single block, 256 threads, 16 elems/thread per chunk
__global__ __launch_bounds__(256) void k_scan(const int* __restrict__ deg, int* __restrict__ rowptr, int N) {
    __shared__ int partial[256];
    __shared__ int s_carry;
    const int t = threadIdx.x;
    if (t == 0) s_carry = 0;
    __syncthreads();
    for (int base = 0; base < N; base += 4096) {
        int v[16];
        int lsum = 0;
        int i0 = base + t * 16;
#pragma unroll
        for (int k = 0; k < 16; k++) {
            int i = i0 + k;
            v[k] = (i < N) ? deg[i] : 0;
            lsum += v[k];
        }
        partial[t] = lsum;
        __syncthreads();
        for (int o = 1; o < 256; o <<= 1) {
            int add = (t >= o) ? partial[t - o] : 0;
            __syncthreads();
            partial[t] += add;
            __syncthreads();
        }
        int excl = s_carry + partial[t] - lsum;
#pragma unroll
        for (int k = 0; k < 16; k++) {
            int i = i0 + k;
            if (i < N) rowptr[i] = excl;
            excl += v[k];
        }
        __syncthreads();
        if (t == 255) s_carry += partial[255];
        __syncthreads();
    }
    if (t == 0) rowptr[N] = s_carry;
}

__global__ __launch_bounds__(256) void k_scatter(const int* __restrict__ ei, const int* __restrict__ rowptr,
                                                 int* __restrict__ cursor, int* __restrict__ csr_src, int E) {
    int e = blockIdx.x * 256 + threadIdx.x;
    if (e >= E) return;
    int d = ei[E + e];
    int pos = atomicAdd(&cursor[d], 1);
    csr_src[rowptr[d] + pos] = ei[e];
}

// ---------------- GEMM1 fused: h1(bf16)+h1c(col255 fp32) = x@W1 ; al1/ar1 ; logr + rwsum ----------------
__global__ __launch_bounds__(256) void k_gemm1f(const void* __restrict__ x,
                                                const void* __restrict__ W,
                                                const void* __restrict__ attl,
                                                const void* __restrict__ attr,
                                                unsigned short* __restrict__ h1,
                                                float* __restrict__ h1c,
                                                float* __restrict__ al1, float* __restrict__ ar1,
                                                float* __restrict__ logr, float* __restrict__ rwS,
                                                int N, const int* __restrict__ flag) {
    const int isbf = *flag;
    __shared__ float xs[16][128];
    __shared__ float rpart[16];
    const int row0 = blockIdx.x * 16;
    const int t = threadIdx.x;
#pragma unroll
    for (int i = 0; i < 8; i++) {
        int idx = t + i * 256;
        int r = idx >> 7, c = idx & 127;
        xs[r][c] = ldf(x, (size_t)(row0 + r) * 128 + c, isbf);
    }
    __syncthreads();
    const int j = t;  // column 0..255; wave w = j>>6 == head
    float acc[16];
#pragma unroll
    for (int r = 0; r < 16; r++) acc[r] = 0.f;
    for (int k = 0; k < 128; k += 4) {
        float w0 = ldf(W, (size_t)(k + 0) * 256 + j, isbf);
        float w1 = ldf(W, (size_t)(k + 1) * 256 + j, isbf);
        float w2 = ldf(W, (size_t)(k + 2) * 256 + j, isbf);
        float w3 = ldf(W, (size_t)(k + 3) * 256 + j, isbf);
#pragma unroll
        for (int r = 0; r < 16; r++) {
            float4 xv = *reinterpret_cast<const float4*>(&xs[r][k]);
            acc[r] += xv.x * w0 + xv.y * w1 + xv.z * w2 + xv.w * w3;
        }
    }
#pragma unroll
    for (int r = 0; r < 16; r++) {
        h1[(size_t)(row0 + r) * 256 + j] = f2bu(acc[r]);
        if (j == 255) h1c[row0 + r] = acc[r];   // fp32 sidecar: log-sensitive column
    }

    // fused stats: wave w reduces head w (cols w*64..w*64+63)
    const int w = t >> 6, lane = t & 63;
    float avl = ldf(attl, j, isbf);
    float avr = ldf(attr, j, isbf);
#pragma unroll
    for (int r = 0; r < 16; r++) {
        float sl = waveReduceSum(acc[r] * avl);
        float sr = waveReduceSum(acc[r] * avr);
        if (lane == 0) {
            al1[(row0 + r) * 4 + w] = sl;
            ar1[(row0 + r) * 4 + w] = sr;
        }
    }
    // fused reward weight: x col 127 is in LDS
    if (t < 16) {
        float a = fabsf(xs[t][127]);
        float rr = 1.f / (a + 1e-6f);
        logr[row0 + t] = logf(rr);
        rpart[t] = rr;
    }
    __syncthreads();
    if (t == 0) {
        float s = 0.f;
#pragma unroll
        for (int i = 0; i < 16; i++) s += rpart[i];
        ATOMIC_ADD_F32(rwS, s);
    }
}

// ---------------- layer1 aggregation: online softmax, pipelined bf16 gather + fp32 col255 ----------------
__global__ __launch_bounds__(256) void k_agg1(const int* __restrict__ rowptr,
                                              const int* __restrict__ csr_src,
                                              const float* __restrict__ al1,
                                              const float* __restrict__ ar1,
                                              const float* __restrict__ logr,
                                              const float* __restrict__ rwS,
                                              const unsigned short* __restrict__ h1,
                                              const float* __restrict__ h1c,
                                              float* __restrict__ x2, int N) {
    int d = blockIdx.x * 4 + (threadIdx.x >> 6);
    if (d >= N) return;
    int lane = threadIdx.x & 63;
    int h = lane >> 4;                 // head for this lane's 4 features
    const float gl = FGW * logf(fmaxf(*rwS, 1e-12f));
    float al_h = al1[d * 4 + h];
    int beg = rowptr[d], end = rowptr[d + 1];
    float m = -INFINITY, sum = 0.f;
    float4 acc = {0.f, 0.f, 0.f, 0.f};
    if (beg < end) {
        int s = csr_src[beg];
        float arv = ar1[s * 4 + h];
        float lg = logr[s];
        float c255 = h1c[s];           // wave-uniform address -> broadcast
        uint2 hb = *reinterpret_cast<const uint2*>(&h1[(size_t)s * 256 + lane * 4]);
        for (int i = beg; i < end; i++) {
            float c_ar = arv, c_lg = lg, c_c255 = c255;
            uint2 c_hb = hb;
            if (i + 1 < end) {  // wave-uniform prefetch of next edge
                int s2 = csr_src[i + 1];
                arv = ar1[s2 * 4 + h];
                lg = logr[s2];
                c255 = h1c[s2];
                hb = *reinterpret_cast<const uint2*>(&h1[(size_t)s2 * 256 + lane * 4]);
            }
            float a = al_h + c_ar;
            a = fmaxf(a, NEG_SLOPE * a);          // leaky_relu
            a = fmaf(FGW, c_lg, a - gl);          // + FGW*(log r - log S)
            float mn = fmaxf(m, a);
            float f = expf(m - mn);               // 0 on first edge
            float e = expf(a - mn);
            sum = sum * f + e;
            float v0 = __uint_as_float(c_hb.x << 16);
            float v1 = __uint_as_float(c_hb.x & 0xFFFF0000u);
            float v2 = __uint_as_float(c_hb.y << 16);
            float v3 = __uint_as_float(c_hb.y & 0xFFFF0000u);
            v3 = (lane == 63) ? c_c255 : v3;      // exact fp32 for the log-sensitive col 255
            acc.x = acc.x * f + e * v0;
            acc.y = acc.y * f + e * v1;
            acc.z = acc.z * f + e * v2;
            acc.w = acc.w * f + e * v3;
            m = mn;
        }
    }
    float inv = 1.f / (sum + 1e-16f);
    float4 o;
    o.x = acc.x * inv; o.y = acc.y * inv; o.z = acc.z * inv; o.w = acc.w * inv;
    o.x = (o.x > 0.f) ? o.x : expm1f(o.x);
    o.y = (o.y > 0.f) ? o.y : expm1f(o.y);
    o.z = (o.z > 0.f) ? o.z : expm1f(o.z);
    o.w = (o.w > 0.f) ? o.w : expm1f(o.w);
    *reinterpret_cast<float4*>(&x2[(size_t)d * 256 + lane * 4]) = o;
}

// ---------------- GEMM2 fused: h2(bf16) = x2@W2 ; al2/ar2 ; logr2 + rwsum2 ----------------
// al2/ar2/logr2 computed from fp32 accumulators/LDS -> unaffected by h2 quantization
__global__ __launch_bounds__(256) void k_gemm2f(const float* __restrict__ x2,
                                                const void* __restrict__ W,
                                                const void* __restrict__ attl,
                                                const void* __restrict__ attr,
                                                unsigned short* __restrict__ h2,
                                                float* __restrict__ al2, float* __restrict__ ar2,
                                                float* __restrict__ logr2, float* __restrict__ rwS2,
                                                int N, const int* __restrict__ flag) {
    const int isbf = *flag;
    __shared__ float xs[16][256];
    __shared__ float rpart[16];
    const int row0 = blockIdx.x * 16;
    const int t = threadIdx.x;
#pragma unroll
    for (int i = 0; i < 16; i++) {
        int idx = t + i * 256;
        int r = idx >> 8, c = idx & 255;
        xs[r][c] = x2[(size_t)(row0 + r) * 256 + c];
    }
    __syncthreads();
    const int j = t & 63, rg = t >> 6;   // wave rg handles rows rg*4..rg*4+3
    float acc[4] = {0.f, 0.f, 0.f, 0.f};
    for (int k = 0; k < 256; k += 4) {
        float w0 = ldf(W, (size_t)(k + 0) * 64 + j, isbf);
        float w1 = ldf(W, (size_t)(k + 1) * 64 + j, isbf);
        float w2 = ldf(W, (size_t)(k + 2) * 64 + j, isbf);
        float w3 = ldf(W, (size_t)(k + 3) * 64 + j, isbf);
#pragma unroll
        for (int i = 0; i < 4; i++) {
            float4 xv = *reinterpret_cast<const float4*>(&xs[rg * 4 + i][k]);
            acc[i] += xv.x * w0 + xv.y * w1 + xv.z * w2 + xv.w * w3;
        }
    }
    float avl = ldf(attl, j, isbf);
    float avr = ldf(attr, j, isbf);
#pragma unroll
    for (int i = 0; i < 4; i++) {
        int row = row0 + rg * 4 + i;
        h2[(size_t)row * 64 + j] = f2bu(acc[i]);
        float sl = waveReduceSum(acc[i] * avl);
        float sr = waveReduceSum(acc[i] * avr);
        if (j == 0) { al2[row] = sl; ar2[row] = sr; }
    }
    // fused reward weight: x2 col 255 (fp32, sidecar-derived) in LDS
    if (t < 16) {
        float a = fabsf(xs[t][255]);
        float rr = 1.f / (a + 1e-6f);
        logr2[row0 + t] = logf(rr);
        rpart[t] = rr;
    }
    __syncthreads();
    if (t == 0) {
        float s = 0.f;
#pragma unroll
        for (int i = 0; i < 16; i++) s += rpart[i];
        ATOMIC_ADD_F32(rwS2, s);
    }
}

// ---------------- layer2 aggregation + ELU + FC -> y (online softmax, pipelined) ----------------
__global__ __launch_bounds__(256) void k_agg2(const int* __restrict__ rowptr,
                                              const int* __restrict__ csr_src,
                                              const float* __restrict__ al2,
                                              const float* __restrict__ ar2,
                                              const float* __restrict__ logr2,
                                              const float* __restrict__ rwS2,
                                              const unsigned short* __restrict__ h2,
                                              const void* __restrict__ fcw,
                                              const void* __restrict__ fcb,
                                              void* __restrict__ y, int N,
                                              const int* __restrict__ flag) {
    const int isbf = *flag;
    int d = blockIdx.x * 4 + (threadIdx.x >> 6);
    if (d >= N) return;
    int lane = threadIdx.x & 63;
    const float gl2 = FGW * logf(fmaxf(*rwS2, 1e-12f));
    float al_d = al2[d];
    int beg = rowptr[d], end = rowptr[d + 1];
    float m = -INFINITY, sum = 0.f, acc = 0.f;
    if (beg < end) {
        int s = csr_src[beg];
        float arv = ar2[s];
        float lg = logr2[s];
        float hvs = bu2f(h2[(size_t)s * 64 + lane]);
        for (int i = beg; i < end; i++) {
            float c_ar = arv, c_lg = lg, c_h = hvs;
            if (i + 1 < end) {
                int s2 = csr_src[i + 1];
                arv = ar2[s2];
                lg = logr2[s2];
                hvs = bu2f(h2[(size_t)s2 * 64 + lane]);
            }
            float a = al_d + c_ar;
            a = fmaxf(a, NEG_SLOPE * a);
            a = fmaf(FGW, c_lg, a - gl2);
            float mn = fmaxf(m, a);
            float f = expf(m - mn);
            float e = expf(a - mn);
            sum = sum * f + e;
            acc = acc * f + e * c_h;
            m = mn;
        }
    }
    float v = acc / (sum + 1e-16f);
    v = (v > 0.f) ? v : expm1f(v);
    float r = waveReduceSum(v * ldf(fcw, lane, isbf));
    if (lane == 0) {
        float o = r + ldf(fcb, 0, isbf);
        if (isbf) ((bf16*)y)[d] = __float2bfloat16(o);
        else      ((float*)y)[d] = o;
    }
}

extern "C" void kernel_launch(void* const* d_in, const int* in_sizes, int n_in,
                              void* d_out, int out_size, void* d_ws, size_t ws_size,
                              hipStream_t stream) {
    const void* x     = d_in[0];
    const int*  ei    = (const int*)d_in[1];
    const void* W1    = d_in[2];
    const void* attl1 = d_in[3];
    const void* attr1 = d_in[4];
    const void* W2    = d_in[5];
    const void* attl2 = d_in[6];
    const void* attr2 = d_in[7];
    const void* fcw   = d_in[8];
    const void* fcb   = d_in[9];

    const int N = in_sizes[0] / 128;  // 50000
    const int E = in_sizes[1] / 2;    // 800000

    // ---- workspace layout (4-byte units unless noted) ----
    float* p = (float*)d_ws;
    unsigned short* h1 = (unsigned short*)p; p += (size_t)N * 128;  // N*256 bf16 = 25.6 MB
    float* h1c    = p; p += (size_t)N;                              // fp32 col-255 sidecar
    float* x2     = p; p += (size_t)N * 256;                        // 51.2 MB
    float* al1    = p; p += (size_t)N * 4;
    float* ar1    = p; p += (size_t)N * 4;
    float* logr   = p; p += (size_t)N;
    float* al2    = p; p += (size_t)N;
    float* ar2    = p; p += (size_t)N;
    float* logr2  = p; p += (size_t)N;
    int* rowptr   = (int*)p; p += (size_t)N + 1;
    int* deg      = (int*)p; p += (size_t)N;   // deg+cursor zeroed in one memset
    int* cursor   = (int*)p; p += (size_t)N;
    int* csr_src  = (int*)p; p += (size_t)E;   // 3.2 MB
    float* sscal  = p; p += 4;                 // [0]=rwsum L1, [1]=rwsum L2, [2]=dtype flag
    int* dflag = (int*)(sscal + 2);

    unsigned short* h2 = h1;   // layer2 bf16 h2 (N*64) overlays h1 region (dead after agg1)

    // ---- zero small accumulators (ws is re-poisoned to 0xAA each call) ----
    hipMemsetAsync(deg,   0, (size_t)N * 2 * 4, stream);   // deg + cursor
    hipMemsetAsync(sscal, 0, 16, stream);

    k_detect<<<1, 64, 0, stream>>>((const unsigned short*)x, dflag);

    // ---- CSR build over dst ----
    k_deg<<<(E + 255) / 256, 256, 0, stream>>>(ei, deg, E);
    k_scan<<<1, 256, 0, stream>>>(deg, rowptr, N);
    k_scatter<<<(E + 255) / 256, 256, 0, stream>>>(ei, rowptr, cursor, csr_src, E);

    // ---- layer 1 ----
    k_gemm1f<<<N / 16, 256, 0, stream>>>(x, W1, attl1, attr1, h1, h1c, al1, ar1,
                                         logr, &sscal[0], N, dflag);
    k_agg1<<<(N + 3) / 4, 256, 0, stream>>>(rowptr, csr_src, al1, ar1, logr,
                                            &sscal[0], h1, h1c, x2, N);

    // ---- layer 2 ----
    k_gemm2f<<<N / 16, 256, 0, stream>>>(x2, W2, attl2, attr2, h2, al2, ar2,
                                         logr2, &sscal[1], N, dflag);
    k_agg2<<<(N + 3) / 4, 256, 0, stream>>>(rowptr, csr_src, al2, ar2, logr2,
                                            &sscal[1], h2, fcw, fcb, d_out, N, dflag);
}